// Round 2
// baseline (2379.397 us; speedup 1.0000x reference)
//
#include <hip/hip_runtime.h>

typedef __bf16  bf16x8 __attribute__((ext_vector_type(8)));
typedef float   f32x4  __attribute__((ext_vector_type(4)));

#define MFMA16(a,b,c) __builtin_amdgcn_mfma_f32_16x16x32_bf16((a),(b),(c),0,0,0)

// bf16 weight arena layout in d_ws (elements)
enum : int {
    OFF_W0 = 0,                      // [256][64]
    OFF_W1 = OFF_W0 + 256 * 64,      // [256][256]
    OFF_W2 = OFF_W1 + 256 * 256,
    OFF_W3 = OFF_W2 + 256 * 256,
    OFF_W4 = OFF_W3 + 256 * 256,     // [256][320]
    OFF_W5 = OFF_W4 + 256 * 320,
    OFF_W6 = OFF_W5 + 256 * 256,
    OFF_W7 = OFF_W6 + 256 * 256,
    OFF_WF = OFF_W7 + 256 * 256,     // [256][256]
    OFF_WD = OFF_WF + 256 * 256,     // [128][288]
    W_TOTAL = OFF_WD + 128 * 288
};

__device__ __forceinline__ unsigned short f2bf(float f) {
    unsigned int u = __float_as_uint(f);
    u += 0x7FFFu + ((u >> 16) & 1u);
    return (unsigned short)(u >> 16);
}

__device__ __forceinline__ void prep_one(const float* __restrict__ src,
                                         unsigned short* __restrict__ dst,
                                         int fout, int Kp, int n1, int n2, int n3,
                                         int idx) {
    int n = idx / Kp;
    int k = idx - n * Kp;
    float v = 0.f;
    if (k < n1)                 v = src[k * fout + n];
    else if (k >= n2 && k < n3) v = src[(k - (n2 - n1)) * fout + n];
    dst[n * Kp + k] = f2bf(v);
}

__global__ void prep_kernel(const float* w0, const float* w1, const float* w2,
                            const float* w3, const float* w4, const float* w5,
                            const float* w6, const float* w7, const float* wf,
                            const float* wd, unsigned short* dst) {
    int i = blockIdx.x * 256 + threadIdx.x;
    if (i < 256 * 64)  { prep_one(w0, dst + OFF_W0, 256,  64,  63,  64,  64, i); return; }
    i -= 256 * 64;
    if (i < 256 * 256) { prep_one(w1, dst + OFF_W1, 256, 256, 256, 256, 256, i); return; }
    i -= 256 * 256;
    if (i < 256 * 256) { prep_one(w2, dst + OFF_W2, 256, 256, 256, 256, 256, i); return; }
    i -= 256 * 256;
    if (i < 256 * 256) { prep_one(w3, dst + OFF_W3, 256, 256, 256, 256, 256, i); return; }
    i -= 256 * 256;
    if (i < 256 * 320) { prep_one(w4, dst + OFF_W4, 256, 320,  63,  64, 320, i); return; }
    i -= 256 * 320;
    if (i < 256 * 256) { prep_one(w5, dst + OFF_W5, 256, 256, 256, 256, 256, i); return; }
    i -= 256 * 256;
    if (i < 256 * 256) { prep_one(w6, dst + OFF_W6, 256, 256, 256, 256, 256, i); return; }
    i -= 256 * 256;
    if (i < 256 * 256) { prep_one(w7, dst + OFF_W7, 256, 256, 256, 256, 256, i); return; }
    i -= 256 * 256;
    if (i < 256 * 256) { prep_one(wf, dst + OFF_WF, 256, 256, 256, 256, 256, i); return; }
    i -= 256 * 256;
    if (i < 128 * 288) { prep_one(wd, dst + OFF_WD, 128, 288, 286, 288, 288, i); return; }
}

struct Params {
    const float* x;
    const unsigned short* Wt;
    const float* b[8];
    const float* bfv;
    const float* bdv;
    const float* wsv;
    const float* bsv;
    const float* wrv;
    const float* brv;
    float* out;
};

// Wave-independent design: each wave owns 16 rows end-to-end, no __syncthreads.
// Activations round-trip through a wave-private 8 KB LDS slice (swizzled).
// xyz + dir input fragments live in registers for the whole kernel.
__global__ __launch_bounds__(256, 3) void nerf_kernel(Params P) {
    __shared__ char HsB[4 * 16 * 512];   // 4 wave-private [16][256] bf16 slices

    const int t    = threadIdx.x;
    const int lane = t & 63;
    const int wave = t >> 6;
    const int lr   = lane & 15;          // A-row / B-col / D-col
    const int lk   = lane >> 4;          // k-group
    const int crow = lk << 2;            // D-row base
    char* Hs = HsB + (wave << 13);
    const int rowBase = (blockIdx.x << 6) | (wave << 4);

    // ---- input fragments (registers, persistent) ----
    const float* xrow = P.x + (size_t)(rowBase + lr) * 93;
    bf16x8 xa0, xa1, da;
#pragma unroll
    for (int j = 0; j < 8; ++j) {
        int c0 = lk * 8 + j;
        int c1 = 32 + lk * 8 + j;
        xa0[j] = (__bf16)xrow[c0];                              // c0 < 32 < 63 always valid
        xa1[j] = (c1 < 63) ? (__bf16)xrow[c1] : (__bf16)0.f;
        da[j]  = (c0 < 30) ? (__bf16)xrow[63 + c0] : (__bf16)0.f;
    }

    // A-fragment read: row=lr, k contiguous 16B; XOR swizzle on bits [6:4]
    auto hsA = [&](int kt) -> bf16x8 {
        int off = (lr * 512 + (kt << 6) + (lk << 4)) ^ ((lr & 7) << 4);
        return *(const bf16x8*)(Hs + off);
    };

    f32x4 acc[16];
    auto zeroAcc = [&] {
#pragma unroll
        for (int i = 0; i < 16; ++i) { f32x4 z = {0.f, 0.f, 0.f, 0.f}; acc[i] = z; }
    };
    // one K=32 step against 16 weight tiles (N=256)
    auto ktStep = [&](bf16x8 a, const unsigned short* W, int Kp, int ktW) {
        const unsigned short* Wk = W + (ktW << 5) + (lk << 3) + (size_t)lr * Kp;
#pragma unroll
        for (int nt = 0; nt < 16; ++nt) {
            bf16x8 b = *(const bf16x8*)(Wk + (size_t)(nt << 4) * Kp);
            acc[nt] = MFMA16(a, b, acc[nt]);
        }
    };
    auto epi = [&](const float* bias, bool dorelu) {
#pragma unroll
        for (int nt = 0; nt < 16; ++nt) {
            int col = (nt << 4) + lr;
            float bv = bias[col];
#pragma unroll
            for (int e = 0; e < 4; ++e) {
                int row = crow + e;
                float z = acc[nt][e] + bv;
                if (dorelu) z = fmaxf(z, 0.f);
                *(__bf16*)(Hs + ((row * 512 + col * 2) ^ ((row & 7) << 4))) = (__bf16)z;
            }
        }
    };

    const unsigned short* Wt = P.Wt;

    auto layerH = [&](const unsigned short* W, const float* bias, bool dorelu) {
        zeroAcc();
#pragma unroll 2
        for (int kt = 0; kt < 8; ++kt) ktStep(hsA(kt), W, 256, kt);
        epi(bias, dorelu);
    };

    // layer 0: K=64 from register xyz frags
    zeroAcc();
    ktStep(xa0, Wt + OFF_W0, 64, 0);
    ktStep(xa1, Wt + OFF_W0, 64, 1);
    epi(P.b[0], true);
    // layers 1-3
    layerH(Wt + OFF_W1, P.b[1], true);
    layerH(Wt + OFF_W2, P.b[2], true);
    layerH(Wt + OFF_W3, P.b[3], true);
    // layer 4: K=320 = [xyz(64) | h(256)]
    zeroAcc();
    ktStep(xa0, Wt + OFF_W4, 320, 0);
    ktStep(xa1, Wt + OFF_W4, 320, 1);
#pragma unroll 2
    for (int kt = 0; kt < 8; ++kt) ktStep(hsA(kt), Wt + OFF_W4, 320, kt + 2);
    epi(P.b[4], true);
    // layers 5-7
    layerH(Wt + OFF_W5, P.b[5], true);
    layerH(Wt + OFF_W6, P.b[6], true);
    layerH(Wt + OFF_W7, P.b[7], true);

    // sigma = h @ ws + bs, straight from layer-7 accumulators
    {
        float sp[4] = {0.f, 0.f, 0.f, 0.f};
#pragma unroll
        for (int nt = 0; nt < 16; ++nt) {
            int col = (nt << 4) + lr;
            float bv = P.b[7][col];
            float w  = P.wsv[col];
#pragma unroll
            for (int e = 0; e < 4; ++e)
                sp[e] += fmaxf(acc[nt][e] + bv, 0.f) * w;
        }
#pragma unroll
        for (int e = 0; e < 4; ++e) {
            sp[e] += __shfl_xor(sp[e], 1);
            sp[e] += __shfl_xor(sp[e], 2);
            sp[e] += __shfl_xor(sp[e], 4);
            sp[e] += __shfl_xor(sp[e], 8);
        }
        if (lr == 0) {
#pragma unroll
            for (int e = 0; e < 4; ++e)
                P.out[(size_t)(rowBase + crow + e) * 4 + 3] = sp[e] + P.bsv[0];
        }
    }

    // xyz_final = h @ wf + bf (no relu) -> Hs
    layerH(Wt + OFF_WF, P.bfv, false);

    // d = relu([xyz_final | dir] @ wd + bd): K=288, N=128 — output stays in regs
    f32x4 accd[8];
#pragma unroll
    for (int i = 0; i < 8; ++i) { f32x4 z = {0.f, 0.f, 0.f, 0.f}; accd[i] = z; }
    auto ktStepD = [&](bf16x8 a, int ktW) {
        const unsigned short* Wk = Wt + OFF_WD + (ktW << 5) + (lk << 3) + (size_t)lr * 288;
#pragma unroll
        for (int nt = 0; nt < 8; ++nt) {
            bf16x8 b = *(const bf16x8*)(Wk + (size_t)(nt << 4) * 288);
            accd[nt] = MFMA16(a, b, accd[nt]);
        }
    };
#pragma unroll 2
    for (int kt = 0; kt < 8; ++kt) ktStepD(hsA(kt), kt);
    ktStepD(da, 8);

    // rgb = sigmoid(d @ wr + br), straight from accd
    {
        float p0[4] = {0.f,0.f,0.f,0.f}, p1[4] = {0.f,0.f,0.f,0.f}, p2[4] = {0.f,0.f,0.f,0.f};
#pragma unroll
        for (int nt = 0; nt < 8; ++nt) {
            int col = (nt << 4) + lr;
            float bv = P.bdv[col];
            float w0 = P.wrv[col * 3 + 0];
            float w1 = P.wrv[col * 3 + 1];
            float w2 = P.wrv[col * 3 + 2];
#pragma unroll
            for (int e = 0; e < 4; ++e) {
                float dv = fmaxf(accd[nt][e] + bv, 0.f);
                p0[e] += dv * w0; p1[e] += dv * w1; p2[e] += dv * w2;
            }
        }
#pragma unroll
        for (int e = 0; e < 4; ++e) {
            p0[e] += __shfl_xor(p0[e], 1); p0[e] += __shfl_xor(p0[e], 2);
            p0[e] += __shfl_xor(p0[e], 4); p0[e] += __shfl_xor(p0[e], 8);
            p1[e] += __shfl_xor(p1[e], 1); p1[e] += __shfl_xor(p1[e], 2);
            p1[e] += __shfl_xor(p1[e], 4); p1[e] += __shfl_xor(p1[e], 8);
            p2[e] += __shfl_xor(p2[e], 1); p2[e] += __shfl_xor(p2[e], 2);
            p2[e] += __shfl_xor(p2[e], 4); p2[e] += __shfl_xor(p2[e], 8);
        }
        if (lr == 0) {
#pragma unroll
            for (int e = 0; e < 4; ++e) {
                size_t o = (size_t)(rowBase + crow + e) * 4;
                P.out[o + 0] = 1.f / (1.f + __expf(-(p0[e] + P.brv[0])));
                P.out[o + 1] = 1.f / (1.f + __expf(-(p1[e] + P.brv[1])));
                P.out[o + 2] = 1.f / (1.f + __expf(-(p2[e] + P.brv[2])));
            }
        }
    }
}

extern "C" void kernel_launch(void* const* d_in, const int* in_sizes, int n_in,
                              void* d_out, int out_size, void* d_ws, size_t ws_size,
                              hipStream_t stream) {
    const float* x = (const float*)d_in[0];
    const float* w[8];
    const float* b[8];
    for (int i = 0; i < 8; ++i) {
        w[i] = (const float*)d_in[1 + 2 * i];
        b[i] = (const float*)d_in[2 + 2 * i];
    }
    const float* wf  = (const float*)d_in[17];
    const float* bfv = (const float*)d_in[18];
    const float* wd  = (const float*)d_in[19];
    const float* bdv = (const float*)d_in[20];
    const float* wsv = (const float*)d_in[21];
    const float* bsv = (const float*)d_in[22];
    const float* wrv = (const float*)d_in[23];
    const float* brv = (const float*)d_in[24];

    unsigned short* Wt = (unsigned short*)d_ws;

    prep_kernel<<<(W_TOTAL + 255) / 256, 256, 0, stream>>>(
        w[0], w[1], w[2], w[3], w[4], w[5], w[6], w[7], wf, wd, Wt);

    Params P;
    P.x = x; P.Wt = Wt;
    for (int i = 0; i < 8; ++i) P.b[i] = b[i];
    P.bfv = bfv; P.bdv = bdv; P.wsv = wsv; P.bsv = bsv; P.wrv = wrv; P.brv = brv;
    P.out = (float*)d_out;

    nerf_kernel<<<262144 / 64, 256, 0, stream>>>(P);
}

// Round 3
// 758.775 us; speedup vs baseline: 3.1358x; 3.1358x over previous
//
#include <hip/hip_runtime.h>

typedef __bf16  bf16x8 __attribute__((ext_vector_type(8)));
typedef float   f32x4  __attribute__((ext_vector_type(4)));

#define MFMA16(a,b,c) __builtin_amdgcn_mfma_f32_16x16x32_bf16((a),(b),(c),0,0,0)

template<int V> struct ic_t { static constexpr int value = V; };

// bf16 weight arena layout in d_ws (elements)
enum : int {
    OFF_W0 = 0,                      // [256][64]
    OFF_W1 = OFF_W0 + 256 * 64,      // [256][256]
    OFF_W2 = OFF_W1 + 256 * 256,
    OFF_W3 = OFF_W2 + 256 * 256,
    OFF_W4 = OFF_W3 + 256 * 256,     // [256][320]
    OFF_W5 = OFF_W4 + 256 * 320,
    OFF_W6 = OFF_W5 + 256 * 256,
    OFF_W7 = OFF_W6 + 256 * 256,
    OFF_WF = OFF_W7 + 256 * 256,     // [256][256]
    OFF_WD = OFF_WF + 256 * 256,     // [128][288]
    W_TOTAL = OFF_WD + 128 * 288
};

__device__ __forceinline__ unsigned short f2bf(float f) {
    unsigned int u = __float_as_uint(f);
    u += 0x7FFFu + ((u >> 16) & 1u);
    return (unsigned short)(u >> 16);
}

__device__ __forceinline__ void prep_one(const float* __restrict__ src,
                                         unsigned short* __restrict__ dst,
                                         int fout, int Kp, int n1, int n2, int n3,
                                         int idx) {
    int n = idx / Kp;
    int k = idx - n * Kp;
    float v = 0.f;
    if (k < n1)                 v = src[k * fout + n];
    else if (k >= n2 && k < n3) v = src[(k - (n2 - n1)) * fout + n];
    dst[n * Kp + k] = f2bf(v);
}

__global__ void prep_kernel(const float* w0, const float* w1, const float* w2,
                            const float* w3, const float* w4, const float* w5,
                            const float* w6, const float* w7, const float* wf,
                            const float* wd, unsigned short* dst) {
    int i = blockIdx.x * 256 + threadIdx.x;
    if (i < 256 * 64)  { prep_one(w0, dst + OFF_W0, 256,  64,  63,  64,  64, i); return; }
    i -= 256 * 64;
    if (i < 256 * 256) { prep_one(w1, dst + OFF_W1, 256, 256, 256, 256, 256, i); return; }
    i -= 256 * 256;
    if (i < 256 * 256) { prep_one(w2, dst + OFF_W2, 256, 256, 256, 256, 256, i); return; }
    i -= 256 * 256;
    if (i < 256 * 256) { prep_one(w3, dst + OFF_W3, 256, 256, 256, 256, 256, i); return; }
    i -= 256 * 256;
    if (i < 256 * 320) { prep_one(w4, dst + OFF_W4, 256, 320,  63,  64, 320, i); return; }
    i -= 256 * 320;
    if (i < 256 * 256) { prep_one(w5, dst + OFF_W5, 256, 256, 256, 256, 256, i); return; }
    i -= 256 * 256;
    if (i < 256 * 256) { prep_one(w6, dst + OFF_W6, 256, 256, 256, 256, 256, i); return; }
    i -= 256 * 256;
    if (i < 256 * 256) { prep_one(w7, dst + OFF_W7, 256, 256, 256, 256, 256, i); return; }
    i -= 256 * 256;
    if (i < 256 * 256) { prep_one(wf, dst + OFF_WF, 256, 256, 256, 256, 256, i); return; }
    i -= 256 * 256;
    if (i < 128 * 288) { prep_one(wd, dst + OFF_WD, 128, 288, 286, 288, 288, i); return; }
}

struct Params {
    const float* x;
    const unsigned short* Wt;
    const float* b[8];
    const float* bfv;
    const float* bdv;
    const float* wsv;
    const float* bsv;
    const float* wrv;
    const float* brv;
    float* out;
};

// Block = 64 rows, 4 waves, N-split (wave w owns 64 output cols).
// Double-buffered LDS activations -> 1 barrier/layer. Pipelined inner loop:
// distance-1 register prefetch of A (LDS) and B (L2) fragments.
__global__ __launch_bounds__(256, 2) void nerf_kernel(Params P) {
    __shared__ char Hs0[32768];   // [64][256] bf16, XOR-swizzled
    __shared__ char Hs1[32768];

    const int t    = threadIdx.x;
    const int lane = t & 63;
    const int wave = t >> 6;
    const int lr   = lane & 15;          // A-row / B-col / D-col within tile
    const int lk   = lane >> 4;          // k-group
    const int crow = lk << 2;            // D-row base
    const int blockRow = blockIdx.x << 6;

    // x fragment: cols [c0,c0+8) of row blockRow+mt*16+lr, zero for c >= lim
    auto ldX = [&](int mt, int c0, int lim) -> bf16x8 {
        const float* xr = P.x + (size_t)(blockRow + (mt << 4) + lr) * 93;
        bf16x8 r;
#pragma unroll
        for (int j = 0; j < 8; ++j) {
            int c = c0 + j;
            r[j] = (c < lim) ? (__bf16)xr[c] : (__bf16)0.f;
        }
        return r;
    };
    // Hs fragment: row = mt*16+lr, 16B contiguous k, swizzle ^((row&7)<<4)
    auto ldH = [&](const char* Hs, int mt, int ktL) -> bf16x8 {
        int row = (mt << 4) + lr;
        int off = (row * 512 + (ktL << 6) + (lk << 4)) ^ ((row & 7) << 4);
        return *(const bf16x8*)(Hs + off);
    };

    // Pipelined GEMM layer: M=64 (4 mt tiles), N = NT*16 per wave, K = KT*32.
    auto gemm = [&](auto KTt, auto NTt, auto&& getA, const unsigned short* W, int Kp,
                    const float* bias, char* dst, bool dorelu) {
        constexpr int KT = decltype(KTt)::value;
        constexpr int NT = decltype(NTt)::value;
        const unsigned short* Wb = W + (size_t)(wave * NT * 16 + lr) * Kp + (lk << 3);
        f32x4 acc[4][NT];
#pragma unroll
        for (int mt = 0; mt < 4; ++mt)
#pragma unroll
            for (int nt = 0; nt < NT; ++nt) { f32x4 z = {0.f,0.f,0.f,0.f}; acc[mt][nt] = z; }

        bf16x8 aC[4], aN[4], bC[NT], bN[NT];
#pragma unroll
        for (int mt = 0; mt < 4; ++mt) { aC[mt] = getA(mt, 0); aN[mt] = aC[mt]; }
#pragma unroll
        for (int nt = 0; nt < NT; ++nt) {
            bC[nt] = *(const bf16x8*)(Wb + (size_t)nt * 16 * Kp);
            bN[nt] = bC[nt];
        }
#pragma unroll
        for (int kt = 0; kt < KT; ++kt) {
            if (kt + 1 < KT) {   // compile-time under full unroll
#pragma unroll
                for (int mt = 0; mt < 4; ++mt) aN[mt] = getA(mt, kt + 1);
#pragma unroll
                for (int nt = 0; nt < NT; ++nt)
                    bN[nt] = *(const bf16x8*)(Wb + (size_t)nt * 16 * Kp + ((kt + 1) << 5));
            }
#pragma unroll
            for (int nt = 0; nt < NT; ++nt) {
#pragma unroll
                for (int mt = 0; mt < 4; ++mt)
                    acc[mt][nt] = MFMA16(aC[mt], bC[nt], acc[mt][nt]);
            }
#pragma unroll
            for (int mt = 0; mt < 4; ++mt) aC[mt] = aN[mt];
#pragma unroll
            for (int nt = 0; nt < NT; ++nt) bC[nt] = bN[nt];
        }
        // epilogue: +bias, relu, bf16, write to dst buffer
#pragma unroll
        for (int nt = 0; nt < NT; ++nt) {
            int col = wave * NT * 16 + (nt << 4) + lr;
            float bv = bias[col];
#pragma unroll
            for (int mt = 0; mt < 4; ++mt) {
#pragma unroll
                for (int e = 0; e < 4; ++e) {
                    int row = (mt << 4) + crow + e;
                    float z = acc[mt][nt][e] + bv;
                    if (dorelu) z = fmaxf(z, 0.f);
                    *(__bf16*)(dst + ((row * 512 + col * 2) ^ ((row & 7) << 4))) = (__bf16)z;
                }
            }
        }
    };

    const unsigned short* Wt = P.Wt;
    char* cur = Hs0;
    char* alt = Hs1;

    // layer 0: K=64 from x -> Hs0
    gemm(ic_t<2>{}, ic_t<4>{},
         [&](int mt, int kt) { return ldX(mt, (kt << 5) + (lk << 3), 63); },
         Wt + OFF_W0, 64, P.b[0], cur, true);
    __syncthreads();

    // layers 1-3 (shared instantiation)
    {
        const unsigned short* Wm[3] = {Wt + OFF_W1, Wt + OFF_W2, Wt + OFF_W3};
        const float* bm[3] = {P.b[1], P.b[2], P.b[3]};
        for (int i = 0; i < 3; ++i) {
            gemm(ic_t<8>{}, ic_t<4>{},
                 [&](int mt, int kt) { return ldH(cur, mt, kt); },
                 Wm[i], 256, bm[i], alt, true);
            __syncthreads();
            char* tmp = cur; cur = alt; alt = tmp;
        }
    }
    // layer 4: K=320 = [xyz(64) | h(256)]
    gemm(ic_t<10>{}, ic_t<4>{},
         [&](int mt, int kt) {
             return (kt < 2) ? ldX(mt, (kt << 5) + (lk << 3), 63) : ldH(cur, mt, kt - 2);
         },
         Wt + OFF_W4, 320, P.b[4], alt, true);
    __syncthreads();
    { char* tmp = cur; cur = alt; alt = tmp; }

    // layers 5-7 + wf (wf: no relu)
    {
        const unsigned short* Wn[4] = {Wt + OFF_W5, Wt + OFF_W6, Wt + OFF_W7, Wt + OFF_WF};
        const float* bn[4] = {P.b[5], P.b[6], P.b[7], P.bfv};
        for (int i = 0; i < 4; ++i) {
            gemm(ic_t<8>{}, ic_t<4>{},
                 [&](int mt, int kt) { return ldH(cur, mt, kt); },
                 Wn[i], 256, bn[i], alt, i < 3);
            __syncthreads();
            char* tmp = cur; cur = alt; alt = tmp;
        }
    }
    // now: cur = xyz_final (wf out), alt = h (layer-7 out, intact)

    // sigma = h @ ws + bs  (4 threads/row; h in alt)
    float sig = 0.f;
    {
        int rr = t >> 2, q = t & 3;
        float sp = 0.f;
#pragma unroll
        for (int j = 0; j < 8; ++j) {
            int cb = q * 64 + j * 8;
            bf16x8 h8 = *(const bf16x8*)(alt + ((rr * 512 + cb * 2) ^ ((rr & 7) << 4)));
#pragma unroll
            for (int e = 0; e < 8; ++e) sp += (float)h8[e] * P.wsv[cb + e];
        }
        sp += __shfl_xor(sp, 1);
        sp += __shfl_xor(sp, 2);
        sig = sp + P.bsv[0];
    }
    __syncthreads();   // sigma reads of alt done before wd overwrites alt

    // d = relu([xyz_final | dir] @ wd + bd): K=288, N=128 -> alt cols 0..127
    gemm(ic_t<9>{}, ic_t<2>{},
         [&](int mt, int kt) {
             return (kt < 8) ? ldH(cur, mt, kt) : ldX(mt, 63 + (lk << 3), 93);
         },
         Wt + OFF_WD, 288, P.bdv, alt, true);
    __syncthreads();

    // rgb = sigmoid(d @ wr + br); fused float4 store {r,g,b,sigma}
    {
        int rr = t >> 2, q = t & 3;
        float c0 = 0.f, c1 = 0.f, c2 = 0.f;
#pragma unroll
        for (int j = 0; j < 4; ++j) {
            int kb = q * 32 + j * 8;
            bf16x8 d8 = *(const bf16x8*)(alt + ((rr * 512 + kb * 2) ^ ((rr & 7) << 4)));
#pragma unroll
            for (int e = 0; e < 8; ++e) {
                float dv = (float)d8[e];
                const float* w = P.wrv + (kb + e) * 3;
                c0 += dv * w[0]; c1 += dv * w[1]; c2 += dv * w[2];
            }
        }
        c0 += __shfl_xor(c0, 1); c0 += __shfl_xor(c0, 2);
        c1 += __shfl_xor(c1, 1); c1 += __shfl_xor(c1, 2);
        c2 += __shfl_xor(c2, 1); c2 += __shfl_xor(c2, 2);
        if (q == 0) {
            float4 o;
            o.x = 1.f / (1.f + __expf(-(c0 + P.brv[0])));
            o.y = 1.f / (1.f + __expf(-(c1 + P.brv[1])));
            o.z = 1.f / (1.f + __expf(-(c2 + P.brv[2])));
            o.w = sig;
            ((float4*)P.out)[blockRow + rr] = o;
        }
    }
}

extern "C" void kernel_launch(void* const* d_in, const int* in_sizes, int n_in,
                              void* d_out, int out_size, void* d_ws, size_t ws_size,
                              hipStream_t stream) {
    const float* x = (const float*)d_in[0];
    const float* w[8];
    const float* b[8];
    for (int i = 0; i < 8; ++i) {
        w[i] = (const float*)d_in[1 + 2 * i];
        b[i] = (const float*)d_in[2 + 2 * i];
    }
    const float* wf  = (const float*)d_in[17];
    const float* bfv = (const float*)d_in[18];
    const float* wd  = (const float*)d_in[19];
    const float* bdv = (const float*)d_in[20];
    const float* wsv = (const float*)d_in[21];
    const float* bsv = (const float*)d_in[22];
    const float* wrv = (const float*)d_in[23];
    const float* brv = (const float*)d_in[24];

    unsigned short* Wt = (unsigned short*)d_ws;

    prep_kernel<<<(W_TOTAL + 255) / 256, 256, 0, stream>>>(
        w[0], w[1], w[2], w[3], w[4], w[5], w[6], w[7], wf, wd, Wt);

    Params P;
    P.x = x; P.Wt = Wt;
    for (int i = 0; i < 8; ++i) P.b[i] = b[i];
    P.bfv = bfv; P.bdv = bdv; P.wsv = wsv; P.bsv = bsv; P.wrv = wrv; P.brv = brv;
    P.out = (float*)d_out;

    nerf_kernel<<<262144 / 64, 256, 0, stream>>>(P);
}

// Round 4
// 605.494 us; speedup vs baseline: 3.9297x; 1.2531x over previous
//
#include <hip/hip_runtime.h>

typedef __bf16  bf16x8 __attribute__((ext_vector_type(8)));
typedef float   f32x4  __attribute__((ext_vector_type(4)));
typedef unsigned int uint32x2 __attribute__((ext_vector_type(2)));

#define MFMA16(a,b,c) __builtin_amdgcn_mfma_f32_16x16x32_bf16((a),(b),(c),0,0,0)

template<int V> struct ic_t { static constexpr int value = V; };

// bf16 weight arena layout in d_ws (elements)
enum : int {
    OFF_W0 = 0,                      // [256][64]
    OFF_W1 = OFF_W0 + 256 * 64,      // [256][256]
    OFF_W2 = OFF_W1 + 256 * 256,
    OFF_W3 = OFF_W2 + 256 * 256,
    OFF_W4 = OFF_W3 + 256 * 256,     // [256][320]
    OFF_W5 = OFF_W4 + 256 * 320,
    OFF_W6 = OFF_W5 + 256 * 256,
    OFF_W7 = OFF_W6 + 256 * 256,
    OFF_WF = OFF_W7 + 256 * 256,     // [256][256]
    OFF_WD = OFF_WF + 256 * 256,     // [128][288]
    W_TOTAL = OFF_WD + 128 * 288
};

__device__ __forceinline__ unsigned short f2bf(float f) {
    unsigned int u = __float_as_uint(f);
    u += 0x7FFFu + ((u >> 16) & 1u);
    return (unsigned short)(u >> 16);
}

__device__ __forceinline__ void prep_one(const float* __restrict__ src,
                                         unsigned short* __restrict__ dst,
                                         int fout, int Kp, int n1, int n2, int n3,
                                         int idx) {
    int n = idx / Kp;
    int k = idx - n * Kp;
    float v = 0.f;
    if (k < n1)                 v = src[k * fout + n];
    else if (k >= n2 && k < n3) v = src[(k - (n2 - n1)) * fout + n];
    dst[n * Kp + k] = f2bf(v);
}

__global__ void prep_kernel(const float* w0, const float* w1, const float* w2,
                            const float* w3, const float* w4, const float* w5,
                            const float* w6, const float* w7, const float* wf,
                            const float* wd, unsigned short* dst) {
    int i = blockIdx.x * 256 + threadIdx.x;
    if (i < 256 * 64)  { prep_one(w0, dst + OFF_W0, 256,  64,  63,  64,  64, i); return; }
    i -= 256 * 64;
    if (i < 256 * 256) { prep_one(w1, dst + OFF_W1, 256, 256, 256, 256, 256, i); return; }
    i -= 256 * 256;
    if (i < 256 * 256) { prep_one(w2, dst + OFF_W2, 256, 256, 256, 256, 256, i); return; }
    i -= 256 * 256;
    if (i < 256 * 256) { prep_one(w3, dst + OFF_W3, 256, 256, 256, 256, 256, i); return; }
    i -= 256 * 256;
    if (i < 256 * 320) { prep_one(w4, dst + OFF_W4, 256, 320,  63,  64, 320, i); return; }
    i -= 256 * 320;
    if (i < 256 * 256) { prep_one(w5, dst + OFF_W5, 256, 256, 256, 256, 256, i); return; }
    i -= 256 * 256;
    if (i < 256 * 256) { prep_one(w6, dst + OFF_W6, 256, 256, 256, 256, 256, i); return; }
    i -= 256 * 256;
    if (i < 256 * 256) { prep_one(w7, dst + OFF_W7, 256, 256, 256, 256, 256, i); return; }
    i -= 256 * 256;
    if (i < 256 * 256) { prep_one(wf, dst + OFF_WF, 256, 256, 256, 256, 256, i); return; }
    i -= 256 * 256;
    if (i < 128 * 288) { prep_one(wd, dst + OFF_WD, 128, 288, 286, 288, 288, i); return; }
}

struct Params {
    const float* x;
    const unsigned short* Wt;
    const float* b[8];
    const float* bfv;
    const float* bdv;
    const float* wsv;
    const float* bsv;
    const float* wrv;
    const float* brv;
    float* out;
};

// 64 rows/block, 4 waves, N-split. Swapped-operand MFMA (D=[neuron][batch])
// -> packed b64 epilogue, bias folded into acc init. Depth-2 B prefetch
// crossing layer boundaries (prefetch next layer's kt0/kt1 before barrier).
__global__ __launch_bounds__(256, 2) void nerf_kernel(Params P) {
    __shared__ char Hs0[32768];   // [64][256] bf16, swz ^((row&7)<<4)
    __shared__ char Hs1[32768];
    __shared__ char Xs[8192];     // [64][64] bf16, swz ^((row&7)<<4)
    __shared__ char Ds[4096];     // [64][32] bf16, swz ^((row&3)<<4)  (in-row!)

    const int t    = threadIdx.x;
    const int lane = t & 63;
    const int wave = t >> 6;
    const int lr   = lane & 15;
    const int lk   = lane >> 4;
    const int blockRow = blockIdx.x << 6;

    // ---- B pipeline (persistent across layers): bp0 = frags[kt], bp1 = frags[kt+1]
    bf16x8 bp0[4], bp1[4], bp2[4];
    {   // preload layer-0 kt0/kt1 (pure global, overlaps staging below)
        const unsigned short* Wb0 = P.Wt + OFF_W0 + (size_t)((wave << 6) + lr) * 64 + (lk << 3);
#pragma unroll
        for (int nt = 0; nt < 4; ++nt) {
            bp0[nt] = *(const bf16x8*)(Wb0 + (size_t)(nt << 4) * 64);
            bp1[nt] = *(const bf16x8*)(Wb0 + (size_t)(nt << 4) * 64 + 32);
        }
    }

    // ---- stage x coalesced into Xs/Ds ----
    {
        const float4* xb = (const float4*)(P.x + (size_t)blockRow * 93);
        for (int i = t; i < 1488; i += 256) {          // 64*93/4
            float4 v = xb[i];
            float vv[4] = {v.x, v.y, v.z, v.w};
#pragma unroll
            for (int j = 0; j < 4; ++j) {
                int e = (i << 2) + j;
                int r = e / 93;
                int c = e - r * 93;
                __bf16 us = (__bf16)vv[j];
                if (c < 63)
                    *(__bf16*)(Xs + ((r * 128 + c * 2) ^ ((r & 7) << 4))) = us;
                else
                    *(__bf16*)(Ds + ((r * 64 + (c - 63) * 2) ^ ((r & 3) << 4))) = us;
            }
        }
        if (t < 64) {  // zero pads: Xs col63, Ds cols 30,31
            int r = t;
            *(__bf16*)(Xs + ((r * 128 + 126) ^ ((r & 7) << 4))) = (__bf16)0.f;
            *(__bf16*)(Ds + ((r * 64 + 60) ^ ((r & 3) << 4))) = (__bf16)0.f;
            *(__bf16*)(Ds + ((r * 64 + 62) ^ ((r & 3) << 4))) = (__bf16)0.f;
        }
    }
    __syncthreads();

    // A-fragment getters (activation rows): row = mt*16+lr, k contiguous 16B
    auto ldH = [&](const char* B, int mt, int kt) -> bf16x8 {
        int row = (mt << 4) + lr;
        int off = (row * 512 + (kt << 6) + (lk << 4)) ^ ((row & 7) << 4);
        return *(const bf16x8*)(B + off);
    };
    auto ldXs = [&](int mt, int kt) -> bf16x8 {
        int row = (mt << 4) + lr;
        int off = (row * 128 + (kt << 6) + (lk << 4)) ^ ((row & 7) << 4);
        return *(const bf16x8*)(Xs + off);
    };
    auto ldDs = [&](int mt) -> bf16x8 {
        int row = (mt << 4) + lr;
        int off = (row * 64 + (lk << 4)) ^ ((row & 3) << 4);
        return *(const bf16x8*)(Ds + off);
    };

    // GEMM layer. KT = K/32, NT = N-tiles/wave (output cols NT*16), NTn = next
    // layer's NT for the cross-layer prefetch (0 = none).
    auto gemm = [&](auto KTt, auto NTt, auto NTnt, auto&& getA,
                    const unsigned short* W, int Kp, const float* bias, bool dorelu,
                    char* dst, const unsigned short* Wn, int Kpn, int cbn) {
        constexpr int KT  = decltype(KTt)::value;
        constexpr int NT  = decltype(NTt)::value;
        constexpr int NTn = decltype(NTnt)::value;
        const int colbase = wave * (NT << 4);
        const unsigned short* Wb = W + (size_t)(colbase + lr) * Kp + (lk << 3);
        const unsigned short* Wbn = (NTn > 0) ? Wn + (size_t)(cbn + lr) * Kpn + (lk << 3) : nullptr;

        // bias folded into acc init (neuron = colbase + nt*16 + lk*4 + e)
        f32x4 acc[4][NT];
        {
            f32x4 bfr[NT];
#pragma unroll
            for (int nt = 0; nt < NT; ++nt)
                bfr[nt] = *(const f32x4*)(bias + colbase + (nt << 4) + (lk << 2));
#pragma unroll
            for (int mt = 0; mt < 4; ++mt)
#pragma unroll
                for (int nt = 0; nt < NT; ++nt) acc[mt][nt] = bfr[nt];
        }

        bf16x8 aC[4], aN[4];
#pragma unroll
        for (int mt = 0; mt < 4; ++mt) { aC[mt] = getA(mt, 0); aN[mt] = aC[mt]; }

#pragma unroll
        for (int kt = 0; kt < KT; ++kt) {
            // B prefetch for index kt+2 (wraps into next layer's kt0/kt1)
            if (kt + 2 < KT) {
#pragma unroll
                for (int nt = 0; nt < NT; ++nt)
                    bp2[nt] = *(const bf16x8*)(Wb + (size_t)(nt << 4) * Kp + ((kt + 2) << 5));
            } else if (NTn > 0) {
#pragma unroll
                for (int nt = 0; nt < (NTn > 0 ? NTn : 1); ++nt)
                    bp2[nt] = *(const bf16x8*)(Wbn + (size_t)(nt << 4) * Kpn + ((kt + 2 - KT) << 5));
            }
            // A prefetch distance 1
            if (kt + 1 < KT) {
#pragma unroll
                for (int mt = 0; mt < 4; ++mt) aN[mt] = getA(mt, kt + 1);
            }
            __builtin_amdgcn_s_setprio(1);
#pragma unroll
            for (int nt = 0; nt < NT; ++nt) {
#pragma unroll
                for (int mt = 0; mt < 4; ++mt)
                    acc[mt][nt] = MFMA16(bp0[nt], aC[mt], acc[mt][nt]);  // swapped: D=[neuron][batch]
            }
            __builtin_amdgcn_s_setprio(0);
#pragma unroll
            for (int nt = 0; nt < 4; ++nt) { bp0[nt] = bp1[nt]; bp1[nt] = bp2[nt]; }
#pragma unroll
            for (int mt = 0; mt < 4; ++mt) aC[mt] = aN[mt];
        }

        // epilogue: relu, pack 2x bf16 via cvt_pk, one b64 LDS write per tile
#pragma unroll
        for (int nt = 0; nt < NT; ++nt) {
#pragma unroll
            for (int mt = 0; mt < 4; ++mt) {
                f32x4 v = acc[mt][nt];
                if (dorelu) {
#pragma unroll
                    for (int e = 0; e < 4; ++e) v[e] = fmaxf(v[e], 0.f);
                }
                unsigned int lo, hi;
                asm("v_cvt_pk_bf16_f32 %0, %1, %2" : "=v"(lo) : "v"(v[0]), "v"(v[1]));
                asm("v_cvt_pk_bf16_f32 %0, %1, %2" : "=v"(hi) : "v"(v[2]), "v"(v[3]));
                int batch = (mt << 4) + lr;
                int off = (batch * 512 + ((colbase + (nt << 4) + (lk << 2)) << 1)) ^ ((batch & 7) << 4);
                uint32x2 w2 = {lo, hi};
                *(uint32x2*)(dst + off) = w2;
            }
        }
    };

    const unsigned short* Wt = P.Wt;
    char* cur = Hs0;
    char* alt = Hs1;

    // L0: K=64 from Xs -> cur; next = W1
    gemm(ic_t<2>{}, ic_t<4>{}, ic_t<4>{},
         [&](int mt, int kt) { return ldXs(mt, kt); },
         Wt + OFF_W0, 64, P.b[0], true, cur, Wt + OFF_W1, 256, wave << 6);
    __syncthreads();

    // L1-3
    {
        const unsigned short* Wc[3] = {Wt + OFF_W1, Wt + OFF_W2, Wt + OFF_W3};
        const unsigned short* Wn[3] = {Wt + OFF_W2, Wt + OFF_W3, Wt + OFF_W4};
        const int Kpn[3] = {256, 256, 320};
        const float* bc[3] = {P.b[1], P.b[2], P.b[3]};
        for (int i = 0; i < 3; ++i) {
            gemm(ic_t<8>{}, ic_t<4>{}, ic_t<4>{},
                 [&](int mt, int kt) { return ldH(cur, mt, kt); },
                 Wc[i], 256, bc[i], true, alt, Wn[i], Kpn[i], wave << 6);
            __syncthreads();
            char* tmp = cur; cur = alt; alt = tmp;
        }
    }

    // L4: K=320 = [xyz(64) | h(256)]; next = W5
    gemm(ic_t<10>{}, ic_t<4>{}, ic_t<4>{},
         [&](int mt, int kt) { return (kt < 2) ? ldXs(mt, kt) : ldH(cur, mt, kt - 2); },
         Wt + OFF_W4, 320, P.b[4], true, alt, Wt + OFF_W5, 256, wave << 6);
    __syncthreads();
    { char* tmp = cur; cur = alt; alt = tmp; }

    // L5-7
    {
        const unsigned short* Wc[3] = {Wt + OFF_W5, Wt + OFF_W6, Wt + OFF_W7};
        const unsigned short* Wn[3] = {Wt + OFF_W6, Wt + OFF_W7, Wt + OFF_WF};
        const float* bc[3] = {P.b[5], P.b[6], P.b[7]};
        for (int i = 0; i < 3; ++i) {
            gemm(ic_t<8>{}, ic_t<4>{}, ic_t<4>{},
                 [&](int mt, int kt) { return ldH(cur, mt, kt); },
                 Wc[i], 256, bc[i], true, alt, Wn[i], 256, wave << 6);
            __syncthreads();
            char* tmp = cur; cur = alt; alt = tmp;
        }
    }
    // cur = h (layer-7 out)

    // sigma = h @ ws + bs (read-only on cur; no barrier needed before WF)
    float sig;
    {
        int rr = t >> 2, q = t & 3;
        float sp = 0.f;
#pragma unroll
        for (int j = 0; j < 8; ++j) {
            int cb = (q << 6) + (j << 3);
            bf16x8 h8 = *(const bf16x8*)(cur + ((rr * 512 + (cb << 1)) ^ ((rr & 7) << 4)));
#pragma unroll
            for (int e = 0; e < 8; ++e) sp += (float)h8[e] * P.wsv[cb + e];
        }
        sp += __shfl_xor(sp, 1);
        sp += __shfl_xor(sp, 2);
        sig = sp + P.bsv[0];
    }

    // xyz_final = h @ wf + bf (no relu); next = WD (NT=2, Kp=288, colbase wave*32)
    gemm(ic_t<8>{}, ic_t<4>{}, ic_t<2>{},
         [&](int mt, int kt) { return ldH(cur, mt, kt); },
         Wt + OFF_WF, 256, P.bfv, false, alt, Wt + OFF_WD, 288, wave << 5);
    __syncthreads();
    { char* tmp = cur; cur = alt; alt = tmp; }
    // cur = xyz_final, alt = h (dead)

    // d = relu([xyz_final | dir] @ wd + bd): KT=9, NT=2; no next
    gemm(ic_t<9>{}, ic_t<2>{}, ic_t<0>{},
         [&](int mt, int kt) { return (kt < 8) ? ldH(cur, mt, kt) : ldDs(mt); },
         Wt + OFF_WD, 288, P.bdv, true, alt, nullptr, 0, 0);
    __syncthreads();

    // rgb = sigmoid(d @ wr + br); fused float4 store {r,g,b,sigma}
    {
        int rr = t >> 2, q = t & 3;
        float c0 = 0.f, c1 = 0.f, c2 = 0.f;
#pragma unroll
        for (int j = 0; j < 4; ++j) {
            int kb = (q << 5) + (j << 3);
            bf16x8 d8 = *(const bf16x8*)(alt + ((rr * 512 + (kb << 1)) ^ ((rr & 7) << 4)));
#pragma unroll
            for (int e = 0; e < 8; ++e) {
                float dv = (float)d8[e];
                const float* w = P.wrv + (kb + e) * 3;
                c0 += dv * w[0]; c1 += dv * w[1]; c2 += dv * w[2];
            }
        }
        c0 += __shfl_xor(c0, 1); c0 += __shfl_xor(c0, 2);
        c1 += __shfl_xor(c1, 1); c1 += __shfl_xor(c1, 2);
        c2 += __shfl_xor(c2, 1); c2 += __shfl_xor(c2, 2);
        if (q == 0) {
            float4 o;
            o.x = 1.f / (1.f + __expf(-(c0 + P.brv[0])));
            o.y = 1.f / (1.f + __expf(-(c1 + P.brv[1])));
            o.z = 1.f / (1.f + __expf(-(c2 + P.brv[2])));
            o.w = sig;
            ((float4*)P.out)[blockRow + rr] = o;
        }
    }
}

extern "C" void kernel_launch(void* const* d_in, const int* in_sizes, int n_in,
                              void* d_out, int out_size, void* d_ws, size_t ws_size,
                              hipStream_t stream) {
    const float* x = (const float*)d_in[0];
    const float* w[8];
    const float* b[8];
    for (int i = 0; i < 8; ++i) {
        w[i] = (const float*)d_in[1 + 2 * i];
        b[i] = (const float*)d_in[2 + 2 * i];
    }
    const float* wf  = (const float*)d_in[17];
    const float* bfv = (const float*)d_in[18];
    const float* wd  = (const float*)d_in[19];
    const float* bdv = (const float*)d_in[20];
    const float* wsv = (const float*)d_in[21];
    const float* bsv = (const float*)d_in[22];
    const float* wrv = (const float*)d_in[23];
    const float* brv = (const float*)d_in[24];

    unsigned short* Wt = (unsigned short*)d_ws;

    prep_kernel<<<(W_TOTAL + 255) / 256, 256, 0, stream>>>(
        w[0], w[1], w[2], w[3], w[4], w[5], w[6], w[7], wf, wd, Wt);

    Params P;
    P.x = x; P.Wt = Wt;
    for (int i = 0; i < 8; ++i) P.b[i] = b[i];
    P.bfv = bfv; P.bdv = bdv; P.wsv = wsv; P.bsv = bsv; P.wrv = wrv; P.brv = brv;
    P.out = (float*)d_out;

    nerf_kernel<<<262144 / 64, 256, 0, stream>>>(P);
}